// Round 1
// baseline (189.702 us; speedup 1.0000x reference)
//
#include <hip/hip_runtime.h>

namespace {

constexpr int L     = 128;   // Lx = Ly = Lz
constexpr int NANG  = 120;
constexpr int SLICE = L * L; // 16384 elements per (b, angle) slice

struct alignas(16) WEntry { float w0, w1; int off0, off1; };

// Block: 256 threads = 4 waves. Wave w handles (x = blockIdx.y, y = blockIdx.x*4 + w).
// Lane l: b = l>>5, z0 = (l&31)*4  -> float4 over z. Covers all 2*128 (b,z) per (x,y).
__global__ __launch_bounds__(256) void bp_kernel(
    const float* __restrict__ image,   // [2,120,128,128]
    const float* __restrict__ angles,  // [120] degrees
    float* __restrict__ out)           // [2,128,128,128]
{
    __shared__ WEntry wtab[4 * NANG];  // per-wave weight tables, 7.5 KiB

    const int x     = blockIdx.y;
    const int ybase = blockIdx.x * 4;
    const int tid   = threadIdx.x;

    const float cx = (L - 1) * 0.5f;

    // ---- Phase 1: per-(x,y,angle) weights into LDS (computed once per block) ----
    for (int e = tid; e < 4 * NANG; e += 256) {
        const int a = e % NANG;
        const int w = e / NANG;
        const float phi = -angles[a] * 0.017453292519943295f; // -deg2rad
        float s, c;
        sincosf(phi, &s, &c);
        const float X = (float)x - cx;
        const float Y = (float)(ybase + w) - cx;
        const float sx = c * X + s * Y + cx;
        const float sy = -s * X + c * Y + cx;
        const float x0f = floorf(sx);
        const float y0f = floorf(sy);
        const float wx = sx - x0f;
        const float wy = sy - y0f;
        const int x0 = (int)x0f;
        const int y0 = (int)y0f;
        const float mx0 = (x0 >= 0  && x0 <  L)     ? 1.f : 0.f;
        const float mx1 = (x0 >= -1 && x0 <= L - 2) ? 1.f : 0.f;
        const float my0 = (y0 >= 0  && y0 <  L)     ? 1.f : 0.f;
        const float my1 = (y0 >= -1 && y0 <= L - 2) ? 1.f : 0.f;
        const float A = (1.f - wx) * mx0 + wx * mx1;
        const int y0c = min(max(y0, 0), L - 1);
        const int y1c = min(max(y0 + 1, 0), L - 1);
        WEntry we;
        we.w0   = (1.f - wy) * my0 * A;
        we.w1   = wy * my1 * A;
        we.off0 = y0c * L;   // element offset of source row inside a slice
        we.off1 = y1c * L;
        wtab[w * NANG + a] = we;
    }
    __syncthreads();

    // ---- Phase 2: accumulate over angles ----
    const int wave = tid >> 6;
    const int lane = tid & 63;
    const int b    = lane >> 5;
    const int z0   = (lane & 31) << 2;
    const int y    = ybase + wave;

    const float* __restrict__ base = image + (size_t)b * NANG * SLICE + z0;
    const WEntry* __restrict__ wt  = &wtab[wave * NANG];

    float4 acc = make_float4(0.f, 0.f, 0.f, 0.f);
    float nrm = 0.f;

#pragma unroll 4
    for (int a = 0; a < NANG; ++a) {
        const WEntry we = wt[a];                  // wave-uniform ds_read_b128 broadcast
        const float* p = base + a * SLICE;
        const float4 v0 = *reinterpret_cast<const float4*>(p + we.off0);
        const float4 v1 = *reinterpret_cast<const float4*>(p + we.off1);
        acc.x = fmaf(we.w0, v0.x, fmaf(we.w1, v1.x, acc.x));
        acc.y = fmaf(we.w0, v0.y, fmaf(we.w1, v1.y, acc.y));
        acc.z = fmaf(we.w0, v0.z, fmaf(we.w1, v1.z, acc.z));
        acc.w = fmaf(we.w0, v0.w, fmaf(we.w1, v1.w, acc.w));
        nrm += we.w0 + we.w1;
    }

    const float inv = 1.f / (nrm + 1e-11f);
    const size_t oidx = (((size_t)b * L + x) * L + y) * L + z0;
    *reinterpret_cast<float4*>(out + oidx) =
        make_float4(acc.x * inv, acc.y * inv, acc.z * inv, acc.w * inv);
}

} // namespace

extern "C" void kernel_launch(void* const* d_in, const int* in_sizes, int n_in,
                              void* d_out, int out_size, void* d_ws, size_t ws_size,
                              hipStream_t stream) {
    const float* image  = (const float*)d_in[0];
    const float* angles = (const float*)d_in[1];
    float* out = (float*)d_out;
    (void)in_sizes; (void)n_in; (void)out_size; (void)d_ws; (void)ws_size;

    dim3 grid(L / 4, L);   // 32 x 128 = 4096 blocks, 4 (x,y) pairs each
    bp_kernel<<<grid, 256, 0, stream>>>(image, angles, out);
}